// Round 5
// baseline (451.258 us; speedup 1.0000x reference)
//
#include <hip/hip_runtime.h>
#include <math.h>

#define NUM_ENT   100000
#define NUM_REL   50
#define NUM_EDGES 200000
#define NNZ       1000000
#define DIM       128
#define BATCH     4096
#define NSEG      (NUM_EDGES + NUM_ENT)             // combined segment count

// ws layout (floats): Xl | Xe | int-region
#define XL_OFF  0
#define XE_OFF  (NUM_ENT * DIM)                     // 12.8M floats
#define INT_OFF (XE_OFF + NUM_EDGES * DIM)          // 38.4M floats
// int region (ints, relative to ib):
//  [zeroed by one memset:] cnt[300000] flag_v[100000] flag_e[200000] nv[1]
//  start[300000] cur[300000] bsum[256] pay[2000000] vlist[24704]
// cnt[e] for edges at [0,200000); cnt_v at [200000,300000). Same for start/cur.
#define CNT_C   0
#define FLAG_V  (CNT_C + NSEG)
#define FLAG_E  (FLAG_V + NUM_ENT)
#define NV_CNT  (FLAG_E + NUM_EDGES)
#define ZERO_N  (NV_CNT + 1)                        // memset span (600001 ints)
#define START_C (ZERO_N)
#define CUR_C   (START_C + NSEG)
#define BSUM_C  (CUR_C + NSEG)
#define PAY_C   (BSUM_C + 256)
#define VLIST   (PAY_C + 2 * NNZ)

// ---------------------------------------------------------------------------
// GEMM fused with lorentz: Y = lorentz(X @ W^T + b).
// Block 256, tile 128x128, K in 4 chunks of 32, 8x8 per thread.
// LDS swizzles (see R5 notes): Xs XOR-row swizzle -> 2-way staging writes,
// conflict-free reads; Ws column-rotation -> 2-way reads. Both keep b128
// alignment. LDS 35.3 KB.
__global__ __launch_bounds__(256, 4) void k_gemm_lorentz(const float* __restrict__ X,
                                                         const float* __restrict__ W,
                                                         const float* __restrict__ bias,
                                                         const float* __restrict__ scale_p,
                                                         float* __restrict__ Y) {
    __shared__ float smem[32 * 128 + 32 * 148];     // 8832 floats = 35328 B
    float* Xs = smem;                               // pos = k*128 + (m ^ ((k&12)<<1))
    float* Ws = smem + 32 * 128;                    // pos = k*148 + j + ((j>>5)<<2)
    float* Ps = Ws;                                 // [128][17] aliased post-compute
    float* Y0 = Xs;                                 // [128]
    float* Ss = Xs + 128;
    float* Ts = Xs + 256;

    const int t = threadIdx.x;
    const int row0 = blockIdx.x * 128;
    const int tx = t & 15, ty = t >> 4;
    const int j0 = tx * 8;
    const int r0 = ty * 8;
    const int wj0 = j0 + ((j0 >> 5) << 2);          // Ws swizzled col base
    const float4* X4 = (const float4*)X;
    const float4* W4 = (const float4*)W;

    float acc[8][8];
#pragma unroll
    for (int i = 0; i < 8; ++i)
#pragma unroll
        for (int j = 0; j < 8; ++j) acc[i][j] = 0.f;

    for (int kc = 0; kc < 4; ++kc) {
#pragma unroll
        for (int i = 0; i < 4; ++i) {
            int q = t + 256 * i;                    // 0..1023
            int r = q >> 3, k4 = q & 7;
            int gr = row0 + r;
            float4 xv = make_float4(0.f, 0.f, 0.f, 0.f);
            if (gr < NUM_ENT) xv = X4[gr * 32 + kc * 8 + k4];
            float4 wv = W4[r * 32 + kc * 8 + k4];
            int kb = 4 * k4;
            int xr = r ^ ((k4 & 3) << 3);           // g(k)=((k>>2)&3)<<3, k=4k4+c
            int wr = r + ((r >> 5) << 2);
            Xs[(kb + 0) * 128 + xr] = xv.x; Xs[(kb + 1) * 128 + xr] = xv.y;
            Xs[(kb + 2) * 128 + xr] = xv.z; Xs[(kb + 3) * 128 + xr] = xv.w;
            Ws[(kb + 0) * 148 + wr] = wv.x; Ws[(kb + 1) * 148 + wr] = wv.y;
            Ws[(kb + 2) * 148 + wr] = wv.z; Ws[(kb + 3) * 148 + wr] = wv.w;
        }
        __syncthreads();
#pragma unroll 8
        for (int k = 0; k < 32; ++k) {
            int gx = (k & 12) << 1;
            float4 xa = *(const float4*)&Xs[k * 128 + (r0 ^ gx)];
            float4 xb = *(const float4*)&Xs[k * 128 + ((r0 + 4) ^ gx)];
            float4 wa = *(const float4*)&Ws[k * 148 + wj0];
            float4 wb = *(const float4*)&Ws[k * 148 + wj0 + 4];
            float xr[8] = {xa.x, xa.y, xa.z, xa.w, xb.x, xb.y, xb.z, xb.w};
            float wr[8] = {wa.x, wa.y, wa.z, wa.w, wb.x, wb.y, wb.z, wb.w};
#pragma unroll
            for (int i = 0; i < 8; ++i)
#pragma unroll
                for (int j = 0; j < 8; ++j)
                    acc[i][j] = fmaf(xr[i], wr[j], acc[i][j]);
        }
        __syncthreads();
    }

    // epilogue: bias + per-row spatial sqnorm partials (LDS reused)
    const float4* b4 = (const float4*)bias;
    float4 bb0 = b4[tx * 2], bb1 = b4[tx * 2 + 1];
    float bj[8] = {bb0.x, bb0.y, bb0.z, bb0.w, bb1.x, bb1.y, bb1.z, bb1.w};
#pragma unroll
    for (int i = 0; i < 8; ++i) {
        float p = 0.f;
#pragma unroll
        for (int j = 0; j < 8; ++j) {
            float yv = acc[i][j] + bj[j];
            acc[i][j] = yv;
            p += yv * yv;
        }
        if (tx == 0) {                      // exclude time col, save col-0
            p -= acc[i][0] * acc[i][0];
            Y0[r0 + i] = acc[i][0];
        }
        Ps[(r0 + i) * 17 + tx] = p;
    }
    __syncthreads();
    if (t < 128) {
        float sq = 0.f;
#pragma unroll
        for (int jj = 0; jj < 16; ++jj) sq += Ps[t * 17 + jj];
        float es = expf(scale_p[0]);
        float y0 = Y0[t];
        float time = es / (1.f + expf(-y0)) + 1.1f;
        Ss[t] = sqrtf((time * time - 1.f) / fmaxf(sq, 1e-8f));
        Ts[t] = time;
    }
    __syncthreads();
    float4* Y4 = (float4*)Y;
#pragma unroll
    for (int i = 0; i < 8; ++i) {
        int gr = row0 + r0 + i;
        if (gr >= NUM_ENT) continue;
        float s = Ss[r0 + i], tm = Ts[r0 + i];
        float4 o0, o1;
        o0.x = (tx == 0) ? tm : acc[i][0] * s;
        o0.y = acc[i][1] * s; o0.z = acc[i][2] * s; o0.w = acc[i][3] * s;
        o1.x = acc[i][4] * s; o1.y = acc[i][5] * s;
        o1.z = acc[i][6] * s; o1.w = acc[i][7] * s;
        Y4[gr * 32 + tx * 2]     = o0;
        Y4[gr * 32 + tx * 2 + 1] = o1;
    }
}

// ---------------------------------------------------------------------------
// Flag + dedup + compact the entities actually read by the output stage.
__global__ __launch_bounds__(256) void k_flagv(const int* __restrict__ e1,
                                               const int* __restrict__ e2,
                                               const int* __restrict__ e3,
                                               const int* __restrict__ e4,
                                               const int* __restrict__ e5,
                                               const int* __restrict__ e6,
                                               int* __restrict__ flag_v,
                                               int* __restrict__ vlist,
                                               int* __restrict__ nv) {
    int i = blockIdx.x * 256 + threadIdx.x;
    if (i >= BATCH) return;
    int idx[6] = {e1[i], e2[i], e3[i], e4[i], e5[i], e6[i]};
#pragma unroll
    for (int k = 0; k < 6; ++k) {
        int v = idx[k];
        if (atomicExch(&flag_v[v], 1) == 0)
            vlist[atomicAdd(nv, 1)] = v;
    }
}

// Histogram into the combined cnt array. Edge counts ungated (cheap, L2-
// resident); vertex counts + edge flags gated on demand.
__global__ __launch_bounds__(256) void k_hist(const int* __restrict__ edges,
                                              const int* __restrict__ vertex,
                                              const int* __restrict__ flag_v,
                                              int* __restrict__ cnt,
                                              int* __restrict__ flag_e) {
    int i = blockIdx.x * 256 + threadIdx.x;
    if (i >= NNZ) return;
    int v = vertex[i], e = edges[i];
    atomicAdd(&cnt[e], 1);
    if (flag_v[v]) {
        atomicAdd(&cnt[NUM_EDGES + v], 1);
        flag_e[e] = 1;               // racy store of 1: fine
    }
}

// Block-level exclusive scan: 2048 elems/block (256 thr x 8).
__global__ __launch_bounds__(256) void k_scan_block(const int* __restrict__ cnt,
                                                    int* __restrict__ out,
                                                    int* __restrict__ bsum, int N) {
    __shared__ int lds[256];
    int t = threadIdx.x;
    int base = blockIdx.x * 2048 + t * 8;
    int a[8];
#pragma unroll
    for (int j = 0; j < 8; ++j) a[j] = (base + j < N) ? cnt[base + j] : 0;
    int local = 0;
#pragma unroll
    for (int j = 0; j < 8; ++j) local += a[j];
    lds[t] = local;
    __syncthreads();
    for (int off = 1; off < 256; off <<= 1) {
        int add = (t >= off) ? lds[t - off] : 0;
        __syncthreads();
        if (t >= off) lds[t] += add;
        __syncthreads();
    }
    int excl = lds[t] - local;
    if (t == 255) bsum[blockIdx.x] = lds[255];
    int s = excl;
#pragma unroll
    for (int j = 0; j < 8; ++j) {
        if (base + j < N) out[base + j] = s;
        s += a[j];
    }
}

__global__ __launch_bounds__(256) void k_scan_top(int* __restrict__ bs, int nb) {
    __shared__ int lds[256];
    int t = threadIdx.x;
    int v = (t < nb) ? bs[t] : 0;
    lds[t] = v;
    __syncthreads();
    for (int off = 1; off < 256; off <<= 1) {
        int add = (t >= off) ? lds[t - off] : 0;
        __syncthreads();
        if (t >= off) lds[t] += add;
        __syncthreads();
    }
    if (t < nb) bs[t] = lds[t] - v;
}

__global__ __launch_bounds__(256) void k_scan_add(int* __restrict__ out,
                                                  int* __restrict__ cur,
                                                  const int* __restrict__ bsum, int N) {
    int i = blockIdx.x * 256 + threadIdx.x;
    if (i >= N) return;
    int v = out[i] + bsum[i >> 11];
    out[i] = v;
    cur[i] = v;
}

// Fill payloads (gated on demand flags). E-side packs (vertex<<9)|ty.
__global__ __launch_bounds__(256) void k_fill(const int* __restrict__ edges,
                                              const int* __restrict__ vertex,
                                              const int* __restrict__ tyi,
                                              const int* __restrict__ flag_e,
                                              const int* __restrict__ flag_v,
                                              int* __restrict__ cur,
                                              int* __restrict__ pay) {
    int i = blockIdx.x * 256 + threadIdx.x;
    if (i >= NNZ) return;
    int v = vertex[i], e = edges[i], tt = tyi[i];
    if (flag_e[e]) {
        int p = atomicAdd(&cur[e], 1);
        pay[p] = (v << 9) | tt;
    }
    if (flag_v[v]) {
        int q = atomicAdd(&cur[NUM_EDGES + v], 1);
        pay[q] = e;
    }
}

// ---------------------------------------------------------------------------
// Xe[e] = sum over contributors (Xl[v] - Ty[tt]), flagged edges only.
// 32 lanes per edge, float4/lane.
__global__ __launch_bounds__(256) void k_gatherE(const float* __restrict__ Xl,
                                                 const float* __restrict__ Ty,
                                                 const int* __restrict__ flag_e,
                                                 const int* __restrict__ start,
                                                 const int* __restrict__ cnt,
                                                 const int* __restrict__ pay,
                                                 float* __restrict__ Xe) {
    int tid = blockIdx.x * 256 + threadIdx.x;
    int e = tid >> 5, l = tid & 31;
    if (e >= NUM_EDGES) return;
    if (!flag_e[e]) return;
    int s = start[e], n = cnt[e];
    const float4* Xl4 = (const float4*)Xl;
    const float4* Ty4 = (const float4*)Ty;
    float4 acc = make_float4(0.f, 0.f, 0.f, 0.f);
    for (int k = 0; k < n; ++k) {
        int pe = pay[s + k];
        int v = pe >> 9, tt = pe & 511;
        float4 a = Xl4[v * 32 + l];
        float4 c = Ty4[tt * 32 + l];
        acc.x += a.x - c.x; acc.y += a.y - c.y;
        acc.z += a.z - c.z; acc.w += a.w - c.w;
    }
    ((float4*)Xe)[e * 32 + l] = acc;
}

// ---------------------------------------------------------------------------
// For flagged vertices only: Xv gather + E_e = logmap0(eps*Xv + Xl) + row-0
// fixup, in place in Xl. One wave per flagged vertex (via vlist).
__global__ __launch_bounds__(256) void k_gatherV_final(float* __restrict__ XlEe,
                                                       const float* __restrict__ Xe,
                                                       const int* __restrict__ start,
                                                       const int* __restrict__ cnt,
                                                       const int* __restrict__ pay,
                                                       const int* __restrict__ vlist,
                                                       const int* __restrict__ nv_p,
                                                       const float* __restrict__ eps_p) {
    int gid = blockIdx.x * 256 + threadIdx.x;
    int idx = gid >> 6, lane = gid & 63;
    if (idx >= nv_p[0]) return;
    int w = vlist[idx];
    int s = start[NUM_EDGES + w], n = cnt[NUM_EDGES + w];
    float sa = 0.f, sb = 0.f;
    for (int k = 0; k < n; ++k) {
        int e = pay[s + k];
        sa += Xe[e * 128 + lane];
        sb += Xe[e * 128 + 64 + lane];
    }
    float eps = eps_p[0];
    float xa = fmaf(eps, sa, XlEe[w * 128 + lane]);
    float xb = fmaf(eps, sb, XlEe[w * 128 + 64 + lane]);
    float x0 = __shfl(xa, 0, 64);
    float sq = xa * xa + xb * xb;
#pragma unroll
    for (int off = 32; off > 0; off >>= 1) sq += __shfl_xor(sq, off, 64);
    sq = fmaxf(sq - x0 * x0, 0.f);
    float ynorm = fmaxf(sqrtf(sq), 1e-8f);
    float theta = fmaxf(x0, 1.f + 1e-7f);
    float fac = logf(theta + sqrtf(theta * theta - 1.f)) / ynorm;  // arccosh
    float oa = (lane == 0) ? 0.f : xa * fac;
    float ob = xb * fac;
    if (w == 0) { oa = 1.f; ob = 1.f; }
    XlEe[w * 128 + lane]      = oa;
    XlEe[w * 128 + 64 + lane] = ob;
}

// ---------------------------------------------------------------------------
// out[b] = sum_j prod(E_e[e1..e6][j]) * R_e[r_idx][j]. Wave per b.
__global__ __launch_bounds__(256) void k_out(const float* __restrict__ Ee,
                                             const float* __restrict__ R,
                                             const int* __restrict__ r_idx,
                                             const int* __restrict__ e1,
                                             const int* __restrict__ e2,
                                             const int* __restrict__ e3,
                                             const int* __restrict__ e4,
                                             const int* __restrict__ e5,
                                             const int* __restrict__ e6,
                                             float* __restrict__ out) {
    int gid = blockIdx.x * 256 + threadIdx.x;
    int b = gid >> 6, lane = gid & 63;
    if (b >= BATCH) return;
    int i1 = e1[b], i2 = e2[b], i3 = e3[b], i4 = e4[b], i5 = e5[b], i6 = e6[b];
    int rr = r_idx[b];
    float pa = Ee[i1 * 128 + lane] * Ee[i2 * 128 + lane] * Ee[i3 * 128 + lane]
             * Ee[i4 * 128 + lane] * Ee[i5 * 128 + lane] * Ee[i6 * 128 + lane];
    float pb = Ee[i1 * 128 + 64 + lane] * Ee[i2 * 128 + 64 + lane] * Ee[i3 * 128 + 64 + lane]
             * Ee[i4 * 128 + 64 + lane] * Ee[i5 * 128 + 64 + lane] * Ee[i6 * 128 + 64 + lane];
    float ra = (rr == 0) ? 1.f : R[rr * 128 + lane];
    float rb = (rr == 0) ? 1.f : R[rr * 128 + 64 + lane];
    float s = pa * ra + pb * rb;
#pragma unroll
    for (int off = 32; off > 0; off >>= 1) s += __shfl_xor(s, off, 64);
    if (lane == 0) out[b] = s;
}

// ---------------------------------------------------------------------------
extern "C" void kernel_launch(void* const* d_in, const int* in_sizes, int n_in,
                              void* d_out, int out_size, void* d_ws, size_t ws_size,
                              hipStream_t stream) {
    const float* emb_E     = (const float*)d_in[0];
    const float* emb_R     = (const float*)d_in[1];
    const float* emb_ty    = (const float*)d_in[2];
    const float* lin_W     = (const float*)d_in[3];
    const float* lin_b     = (const float*)d_in[4];
    const float* lin_scale = (const float*)d_in[5];
    const float* eps       = (const float*)d_in[6];
    const int* r_idx  = (const int*)d_in[8];
    const int* e1     = (const int*)d_in[9];
    const int* e2     = (const int*)d_in[10];
    const int* e3     = (const int*)d_in[11];
    const int* e4     = (const int*)d_in[12];
    const int* e5     = (const int*)d_in[13];
    const int* e6     = (const int*)d_in[14];
    const int* vertex = (const int*)d_in[15];
    const int* edges  = (const int*)d_in[16];
    const int* tyi    = (const int*)d_in[17];

    float* ws = (float*)d_ws;
    float* Xl = ws + XL_OFF;   // 100000 x 128, becomes E_e in place
    float* Xe = ws + XE_OFF;   // 200000 x 128
    int*   ib = (int*)(ws + INT_OFF);
    int* cnt    = ib + CNT_C;
    int* flag_v = ib + FLAG_V;
    int* flag_e = ib + FLAG_E;
    int* nv     = ib + NV_CNT;
    int* start  = ib + START_C;
    int* cur    = ib + CUR_C;
    int* bsum   = ib + BSUM_C;
    int* pay    = ib + PAY_C;
    int* vlist  = ib + VLIST;

    // zero cnt|flag_v|flag_e|nv in one shot
    hipMemsetAsync(cnt, 0, (size_t)ZERO_N * sizeof(int), stream);

    const int NB = (NSEG + 2047) / 2048;   // 147 <= 256

    k_flagv<<<(BATCH + 255) / 256, 256, 0, stream>>>(e1, e2, e3, e4, e5, e6,
                                                     flag_v, vlist, nv);
    k_hist<<<(NNZ + 255) / 256, 256, 0, stream>>>(edges, vertex, flag_v, cnt, flag_e);
    k_scan_block<<<NB, 256, 0, stream>>>(cnt, start, bsum, NSEG);
    k_scan_top<<<1, 256, 0, stream>>>(bsum, NB);
    k_scan_add<<<(NSEG + 255) / 256, 256, 0, stream>>>(start, cur, bsum, NSEG);
    k_fill<<<(NNZ + 255) / 256, 256, 0, stream>>>(edges, vertex, tyi, flag_e, flag_v,
                                                  cur, pay);

    k_gemm_lorentz<<<(NUM_ENT + 127) / 128, 256, 0, stream>>>(emb_E, lin_W, lin_b,
                                                              lin_scale, Xl);
    k_gatherE<<<(NUM_EDGES * 32) / 256, 256, 0, stream>>>(Xl, emb_ty, flag_e,
                                                          start, cnt, pay, Xe);
    k_gatherV_final<<<(BATCH * 6 * 64) / 256, 256, 0, stream>>>(Xl, Xe, start, cnt,
                                                                pay, vlist, nv, eps);
    k_out<<<(BATCH * 64) / 256, 256, 0, stream>>>(Xl, emb_R, r_idx,
                                                  e1, e2, e3, e4, e5, e6,
                                                  (float*)d_out);
}